// Round 10
// baseline (71.195 us; speedup 1.0000x reference)
//
#include <hip/hip_runtime.h>

#define FG 15
#define NPROP 512
#define NCLS 16
#define NCI 30   // B*FG
#define SCORE_T 0.05f
#define NMS_T 0.5f
#define DETS 100
#define STAGE_CAP 4096

typedef unsigned long long u64;
typedef unsigned int u32;

__device__ __forceinline__ unsigned sortable_f32(float f) {
  unsigned u = __float_as_uint(f);
  return u ^ ((u >> 31) ? 0xFFFFFFFFu : 0x80000000u);
}

// ---------------- register Sutherland-Hodgman (fast-math; IoU slack >> rounding) --------
#define CLIP_EMIT(V, VALIDEXPR, CX, CY, NX, NY)                                \
  {                                                                            \
    bool valid = (VALIDEXPR);                                                  \
    float cx = (CX), cy = (CY), nx = (NX), ny = (NY);                          \
    float sc = ex * (cy - p1y) - ey * (cx - p1x);                              \
    float sn = ex * (ny - p1y) - ey * (nx - p1x);                              \
    bool ic = sc >= 0.f, inn = sn >= 0.f;                                      \
    float den = sc - sn;                                                       \
    float dsel = (fabsf(den) > 1e-8f) ? den : 1.f;                             \
    float tt = sc * __builtin_amdgcn_rcpf(dsel);                               \
    float qx = cx + tt * (nx - cx);                                            \
    float qy = cy + tt * (ny - cy);                                            \
    bool fC = valid && ic;                                                     \
    bool fI = valid && (ic != inn);                                            \
    _Pragma("unroll") for (int o = 0; o < 8; ++o) if (o <= 2 * (V)) {          \
      bool wr = fC && (m == o);                                                \
      ox[o] = wr ? cx : ox[o];                                                 \
      oy[o] = wr ? cy : oy[o];                                                 \
    }                                                                          \
    m += fC ? 1 : 0;                                                           \
    _Pragma("unroll") for (int o = 0; o < 8; ++o) if (o <= 2 * (V) + 1) {      \
      bool wr = fI && (m == o);                                                \
      ox[o] = wr ? qx : ox[o];                                                 \
      oy[o] = wr ? qy : oy[o];                                                 \
    }                                                                          \
    m += fI ? 1 : 0;                                                           \
  }

__device__ __forceinline__ float inter_area_fast(const float (&Ax)[4], const float (&Ay)[4],
                                                 const float (&Bx)[4], const float (&By)[4]) {
  float inx[8], iny[8];
  int n = 4;
#pragma unroll
  for (int v = 0; v < 4; ++v) {
    inx[v] = Ax[v]; iny[v] = Ay[v];
    inx[v + 4] = 0.f; iny[v + 4] = 0.f;
  }
#pragma unroll
  for (int e = 0; e < 4; ++e) {
    int e2 = (e + 1) & 3;
    float p1x = Bx[e], p1y = By[e];
    float ex = Bx[e2] - p1x, ey = By[e2] - p1y;
    float ox[8], oy[8];
    int m = 0;
#pragma unroll
    for (int o = 0; o < 8; ++o) { ox[o] = 0.f; oy[o] = 0.f; }
    if (e == 0) {  // n == 4 statically
#pragma unroll
      for (int v = 0; v < 4; ++v) {
        CLIP_EMIT(v, true, inx[v], iny[v], inx[(v + 1) & 3], iny[(v + 1) & 3]);
      }
    } else {
#pragma unroll
      for (int v = 0; v < 8; ++v) {
        bool wrap = (v + 1 >= n);
        CLIP_EMIT(v, v < n, inx[v], iny[v],
                  wrap ? inx[0] : inx[(v + 1) & 7],
                  wrap ? iny[0] : iny[(v + 1) & 7]);
      }
    }
    n = (m < 8) ? m : 8;
#pragma unroll
    for (int o = 0; o < 8; ++o) { inx[o] = ox[o]; iny[o] = oy[o]; }
  }
  float s = 0.f;
#pragma unroll
  for (int v = 0; v < 8; ++v) {
    bool valid = v < n;
    bool wrap = (v + 1 >= n);
    float axx = inx[v], ayy = iny[v];
    float bxx = wrap ? inx[0] : inx[(v + 1) & 7];
    float byy = wrap ? iny[0] : iny[(v + 1) & 7];
    float cr = axx * byy - bxx * ayy;
    s += valid ? cr : 0.f;
  }
  float area = 0.5f * fabsf(s);
  return (n >= 3) ? area : 0.f;
}

// ---------------- kernel 1: full per-class pipeline, one block per ci ----------------
// decode+softmax -> rank sort -> corners/AABB -> wave-parallel triangular AABB
// filter -> staged clip (mask via LDS atomicOr, never global) -> register-scan
// greedy NMS -> kkey. Only bsort (topk box gather) and kkey leave the block.
__global__ void __launch_bounds__(512) k_mega(
    const float* __restrict__ logits, const float* __restrict__ regr,
    const float* __restrict__ prop,
    float* __restrict__ bsort,    // [NCI][NPROP][5] sorted boxes
    u64* __restrict__ kkey) {     // [NCI][128] kept keys, desc, 0-filled
  int ci = blockIdx.x;
  int b = ci / FG, c = ci - b * FG + 1;  // class 1..15
  int tid = threadIdx.x, lane = tid & 63, wv = tid >> 6;

  __shared__ __align__(16) u64 key[NPROP];          //  4 KB
  __shared__ float ssl[NPROP];                      //  2 KB sorted masked scores
  __shared__ __align__(16) float crn[NPROP][8];     // 16 KB sorted corners
  __shared__ float4 aabb[NPROP];                    //  8 KB
  __shared__ float areaL[NPROP];                    //  2 KB
  __shared__ u32 stage[STAGE_CAP];                  // 16 KB
  __shared__ u64 maskl[(NPROP + 4) * 8];            // 33 KB (+4 pad rows for prefetch)
  __shared__ u64 keptw[8];
  __shared__ int wpre[8];
  __shared__ int vloc, lcnt;

  if (tid == 0) { vloc = NPROP; lcnt = 0; }
  for (int x = tid; x < (NPROP + 4) * 8; x += 512) maskl[x] = 0ull;

  // ---- decode + softmax (bit-identical to reference path) ----
  float sc, bb[5];
  {
#pragma clang fp contract(off)
    int g = b * NPROP + tid;
    const float* lg = logits + g * NCLS;
    float l[NCLS];
    float mx = -INFINITY;
#pragma unroll
    for (int q = 0; q < NCLS; ++q) { l[q] = lg[q]; mx = fmaxf(mx, l[q]); }
    float sum = 0.f, ec = 0.f;
#pragma unroll
    for (int q = 0; q < NCLS; ++q) {
      float e = expf(l[q] - mx);
      sum += e;
      if (q == c) ec = e;
    }
    sc = ec / sum;
    const float* pb = prop + g * 5;
    float xc = pb[0], yc = pb[1], w = pb[2], h = pb[3], a = pb[4];
    const float* r = regr + g * 80 + c * 5;
    float dx = r[0] / 10.0f;
    float dy = r[1] / 10.0f;
    float dw = fminf(r[2] / 5.0f, 4.135166556742356f);
    float dh = fminf(r[3] / 5.0f, 4.135166556742356f);
    float da = r[4] / 10.0f;
    bb[0] = dx * w + xc;
    bb[1] = dy * h + yc;
    bb[2] = expf(dw) * w;
    bb[3] = expf(dh) * h;
    bb[4] = da * 57.29577951308232f + a;
    float m = (sc > SCORE_T) ? sc : -INFINITY;
    key[tid] = ((u64)(~sortable_f32(m)) << 32) | (u32)tid;  // asc key = desc score, asc idx
  }
  __syncthreads();

  // ---- rank = #smaller keys (keys strictly distinct => bijective scatter) ----
  int rank = 0;
  {
    u64 myk = key[tid];
    const ulonglong2* k2 = (const ulonglong2*)key;
#pragma unroll 4
    for (int m = 0; m < NPROP / 2; ++m) {
      ulonglong2 kk = k2[m];  // ds_read_b128 broadcast
      rank += (kk.x < myk) ? 1 : 0;
      rank += (kk.y < myk) ? 1 : 0;
    }
  }
  // corners + AABB + area (exact contract-off expressions), scatter by rank
  {
#pragma clang fp contract(off)
    float t = bb[4] * 0.017453292519943295f;
    float cs = cosf(t), sn = sinf(t);
    float hw = bb[2] * 0.5f, hh = bb[3] * 0.5f;
    float lx[4] = {-hw, hw, hw, -hw};
    float ly[4] = {-hh, -hh, hh, hh};
    float X[4], Y[4];
#pragma unroll
    for (int k = 0; k < 4; ++k) {
      X[k] = bb[0] + lx[k] * cs - ly[k] * sn;
      Y[k] = bb[1] + lx[k] * sn + ly[k] * cs;
    }
#pragma unroll
    for (int k = 0; k < 4; ++k) { crn[rank][k] = X[k]; crn[rank][4 + k] = Y[k]; }
    float xmn = fminf(fminf(X[0], X[1]), fminf(X[2], X[3]));
    float xmx = fmaxf(fmaxf(X[0], X[1]), fmaxf(X[2], X[3]));
    float ymn = fminf(fminf(Y[0], Y[1]), fminf(Y[2], Y[3]));
    float ymx = fmaxf(fmaxf(Y[0], Y[1]), fmaxf(Y[2], Y[3]));
    aabb[rank] = make_float4(xmn, ymn, xmx, ymx);
    areaL[rank] = bb[2] * bb[3];
  }
  bool val = sc > SCORE_T;
  ssl[rank] = val ? sc : -INFINITY;
  if (!val) atomicMin(&vloc, rank);
  {  // publish sorted boxes for k_topk's gather
    float* dst = bsort + ((size_t)ci * NPROP + rank) * 5;
#pragma unroll
    for (int q = 0; q < 5; ++q) dst[q] = bb[q];
  }
  __syncthreads();
  int V = vloc;
  int nch = (V + 63) >> 6;

  // ---- phase 1: triangular AABB filter (wave w owns i == w mod 8) ----
  // IoU>0.5 needs inter > (A+B)/3 and inter <= AABB-overlap-area, so require
  // AABBinter > 0.33*(A+B) (1% slack >> fp rounding; AABB-disjoint => inter==0).
  for (int i = wv; i < V; i += 8) {
    float4 ai = aabb[i];
    float Ai = areaL[i];
    for (int ch = i >> 6; ch < nch; ++ch) {
      int j = (ch << 6) | lane;
      bool pass = false;
      if (j > i && j < V) {
        float4 aj = aabb[j];
        float ix = fminf(ai.z, aj.z) - fmaxf(ai.x, aj.x);
        float iy = fminf(ai.w, aj.w) - fmaxf(ai.y, aj.y);
        float ov = fmaxf(ix, 0.f) * fmaxf(iy, 0.f);  // >= exact quad intersection
        pass = ov > 0.33f * (Ai + areaL[j]);
      }
      u64 bal = __ballot(pass);
      if (bal) {
        int base = 0;
        if (lane == 0) base = atomicAdd(&lcnt, (int)__popcll(bal));
        base = __shfl(base, 0);
        if (pass) {
          int pos = base + (int)__popcll(bal & ((1ull << lane) - 1ull));
          if (pos < STAGE_CAP) stage[pos] = ((u32)i << 9) | (u32)j;
        }
      }
    }
  }
  __syncthreads();
  int tot = lcnt < STAGE_CAP ? lcnt : STAGE_CAP;

  // ---- phase 2: clip staged pairs, set LDS mask bits ----
  for (int p = tid; p < tot; p += 512) {
    u32 w = stage[p];
    int i = w >> 9, j = w & 511;
    float4 a0 = *(const float4*)&crn[i][0];
    float4 a1 = *(const float4*)&crn[i][4];
    float4 b0 = *(const float4*)&crn[j][0];
    float4 b1 = *(const float4*)&crn[j][4];
    float Ax[4] = {a0.x, a0.y, a0.z, a0.w};
    float Ay[4] = {a1.x, a1.y, a1.z, a1.w};
    float Bx[4] = {b0.x, b0.y, b0.z, b0.w};
    float By[4] = {b1.x, b1.y, b1.z, b1.w};
    float inter = inter_area_fast(Ax, Ay, Bx, By);
    float areaA = areaL[i];
    float areaB = areaL[j];
    float uni = (areaA + areaB) - inter;
    float iou = inter / fmaxf(uni, 1e-8f);
    if (iou > NMS_T)
      atomicOr(&maskl[i * 8 + (j >> 6)], 1ull << (j & 63));
  }
  __syncthreads();

  // ---- phase 3: greedy NMS register scan (thread 0, 4-deep LDS prefetch) ----
  if (tid == 0) {
    u64 rem[8] = {0, 0, 0, 0, 0, 0, 0, 0};
    u64 kept[8] = {0, 0, 0, 0, 0, 0, 0, 0};
    u64 buf[4][8];
#pragma unroll
    for (int d = 0; d < 4; ++d)
#pragma unroll
      for (int w = 0; w < 8; ++w) buf[d][w] = maskl[d * 8 + w];
    int kc = 0;
    bool stop = (V == 0);
#pragma unroll
    for (int w8 = 0; w8 < 8; ++w8) {
      int lim = V - (w8 << 6);
      lim = lim > 64 ? 64 : lim;
      if (!stop && lim > 0) {
        int lim4 = (lim + 3) & ~3;
        for (int bp4 = 0; bp4 < lim4 && !stop; bp4 += 4) {
#pragma unroll
          for (int d = 0; d < 4; ++d) {
            int bp = bp4 + d;
            int i = (w8 << 6) | bp;
            if (bp < lim && !stop) {
              if (!((rem[w8] >> bp) & 1ull)) {
                kept[w8] |= 1ull << bp;
#pragma unroll
                for (int w = 0; w < 8; ++w) rem[w] |= buf[d][w];
                if (++kc >= DETS) stop = true;  // first 100 kept determine output
              }
            }
#pragma unroll
            for (int w = 0; w < 8; ++w) buf[d][w] = maskl[(i + 4) * 8 + w];  // prefetch
          }
        }
      }
    }
#pragma unroll
    for (int w = 0; w < 8; ++w) keptw[w] = kept[w];
    int acc = 0;
#pragma unroll
    for (int w = 0; w < 8; ++w) { wpre[w] = acc; acc += (int)__popcll(keptw[w]); }
  }
  __syncthreads();

  // ---- phase 4: kkey emit (compacted, desc order by construction) ----
  {
    int i = tid;
    int cfg = c - 1;
    u64 kw = keptw[i >> 6];
    if ((kw >> (i & 63)) & 1ull) {
      int rk = wpre[i >> 6] + (int)__popcll(kw & ((1ull << (i & 63)) - 1ull));
      float s = ssl[i];
      u32 hi = __float_as_uint(s) ^ 0x80000000u;  // s > 0.05 > 0
      u32 flat = (u32)(cfg * NPROP + i);
      kkey[ci * 128 + rk] = ((u64)hi << 32) | (u32)(~flat);  // ties: lower flat wins max
    }
    int total = wpre[7] + (int)__popcll(keptw[7]);
    if (i < 128 && i >= total) kkey[ci * 128 + i] = 0ull;
  }
}

// ---------------- kernel 2: parallel rank-select top-100 ----------------
__global__ void __launch_bounds__(1024) k_topk(
    const u64* __restrict__ kkey,
    const float* __restrict__ bsort,
    float* __restrict__ out) {
  int b = blockIdx.x;  // 2 blocks, 1024 threads
  __shared__ u64 lk[FG * 128];  // 15 KiB
  __shared__ u64 res[DETS];
  for (int x = threadIdx.x; x < FG * 128; x += 1024) lk[x] = kkey[b * FG * 128 + x];
  for (int x = threadIdx.x; x < DETS; x += 1024) res[x] = 0ull;
  __syncthreads();
  for (int x = threadIdx.x; x < FG * 128; x += 1024) {
    u64 key = lk[x];
    if (key == 0ull) continue;  // real keys have hi bit set (score > 0)
    int rank = 0;
#pragma unroll
    for (int c = 0; c < FG; ++c) {
      const u64* a = &lk[c * 128];
      int pos = 0;
#pragma unroll
      for (int st = 64; st > 0; st >>= 1)
        pos += (a[pos + st - 1] > key) ? st : 0;  // pos in [0,127]
      rank += pos + ((a[pos] > key) ? 1 : 0);
    }
    if (rank < DETS) res[rank] = key;
  }
  __syncthreads();
  if (threadIdx.x < DETS) {
    u64 key = res[threadIdx.x];
    float* o = out + ((size_t)b * DETS + threadIdx.x) * 6;
    if (key == 0ull) {
#pragma unroll
      for (int q = 0; q < 6; ++q) o[q] = 0.f;
    } else {
      u32 flat = ~(u32)(key & 0xFFFFFFFFull);
      int cfg = flat >> 9, pos = flat & 511;
      const float* bx = bsort + (((size_t)b * FG + cfg) * NPROP + pos) * 5;
#pragma unroll
      for (int q = 0; q < 5; ++q) o[q] = bx[q];
      o[5] = __uint_as_float((u32)(key >> 32) ^ 0x80000000u);
    }
  }
}

extern "C" void kernel_launch(void* const* d_in, const int* in_sizes, int n_in,
                              void* d_out, int out_size, void* d_ws, size_t ws_size,
                              hipStream_t stream) {
  const float* logits = (const float*)d_in[0];
  const float* regr   = (const float*)d_in[1];
  const float* prop   = (const float*)d_in[2];
  float* out = (float*)d_out;

  float* bsort = (float*)d_ws;                     // NCI*NPROP*5 floats
  u64* kkey    = (u64*)(bsort + NCI * NPROP * 5);  // NCI*128 u64 (307200 B offset, 8-aligned)

  hipLaunchKernelGGL(k_mega, dim3(NCI), dim3(512), 0, stream,
                     logits, regr, prop, bsort, kkey);
  hipLaunchKernelGGL(k_topk, dim3(2), dim3(1024), 0, stream, kkey, bsort, out);
}

// Round 12
// 51.997 us; speedup vs baseline: 1.3692x; 1.3692x over previous
//
#include <hip/hip_runtime.h>

#define FG 15
#define NPROP 512
#define NCLS 16
#define NCI 30   // B*FG
#define SCORE_T 0.05f
#define NMS_T 0.5f
#define DETS 100
#define STRIPES 8
#define STAGE_CAP 4096

typedef unsigned long long u64;
typedef unsigned int u32;

__device__ __forceinline__ unsigned sortable_f32(float f) {
  unsigned u = __float_as_uint(f);
  return u ^ ((u >> 31) ? 0xFFFFFFFFu : 0x80000000u);
}

// ---------------- register Sutherland-Hodgman (fast-math; IoU slack >> rounding) --------
#define CLIP_EMIT(V, VALIDEXPR, CX, CY, NX, NY)                                \
  {                                                                            \
    bool valid = (VALIDEXPR);                                                  \
    float cx = (CX), cy = (CY), nx = (NX), ny = (NY);                          \
    float sc = ex * (cy - p1y) - ey * (cx - p1x);                              \
    float sn = ex * (ny - p1y) - ey * (nx - p1x);                              \
    bool ic = sc >= 0.f, inn = sn >= 0.f;                                      \
    float den = sc - sn;                                                       \
    float dsel = (fabsf(den) > 1e-8f) ? den : 1.f;                             \
    float tt = sc * __builtin_amdgcn_rcpf(dsel);                               \
    float qx = cx + tt * (nx - cx);                                            \
    float qy = cy + tt * (ny - cy);                                            \
    bool fC = valid && ic;                                                     \
    bool fI = valid && (ic != inn);                                            \
    _Pragma("unroll") for (int o = 0; o < 8; ++o) if (o <= 2 * (V)) {          \
      bool wr = fC && (m == o);                                                \
      ox[o] = wr ? cx : ox[o];                                                 \
      oy[o] = wr ? cy : oy[o];                                                 \
    }                                                                          \
    m += fC ? 1 : 0;                                                           \
    _Pragma("unroll") for (int o = 0; o < 8; ++o) if (o <= 2 * (V) + 1) {      \
      bool wr = fI && (m == o);                                                \
      ox[o] = wr ? qx : ox[o];                                                 \
      oy[o] = wr ? qy : oy[o];                                                 \
    }                                                                          \
    m += fI ? 1 : 0;                                                           \
  }

__device__ __forceinline__ float inter_area_fast(const float (&Ax)[4], const float (&Ay)[4],
                                                 const float (&Bx)[4], const float (&By)[4]) {
  float inx[8], iny[8];
  int n = 4;
#pragma unroll
  for (int v = 0; v < 4; ++v) {
    inx[v] = Ax[v]; iny[v] = Ay[v];
    inx[v + 4] = 0.f; iny[v + 4] = 0.f;
  }
#pragma unroll
  for (int e = 0; e < 4; ++e) {
    int e2 = (e + 1) & 3;
    float p1x = Bx[e], p1y = By[e];
    float ex = Bx[e2] - p1x, ey = By[e2] - p1y;
    float ox[8], oy[8];
    int m = 0;
#pragma unroll
    for (int o = 0; o < 8; ++o) { ox[o] = 0.f; oy[o] = 0.f; }
    if (e == 0) {  // n == 4 statically
#pragma unroll
      for (int v = 0; v < 4; ++v) {
        CLIP_EMIT(v, true, inx[v], iny[v], inx[(v + 1) & 3], iny[(v + 1) & 3]);
      }
    } else {
#pragma unroll
      for (int v = 0; v < 8; ++v) {
        bool wrap = (v + 1 >= n);
        CLIP_EMIT(v, v < n, inx[v], iny[v],
                  wrap ? inx[0] : inx[(v + 1) & 7],
                  wrap ? iny[0] : iny[(v + 1) & 7]);
      }
    }
    n = (m < 8) ? m : 8;
#pragma unroll
    for (int o = 0; o < 8; ++o) { inx[o] = ox[o]; iny[o] = oy[o]; }
  }
  float s = 0.f;
#pragma unroll
  for (int v = 0; v < 8; ++v) {
    bool valid = v < n;
    bool wrap = (v + 1 >= n);
    float axx = inx[v], ayy = iny[v];
    float bxx = wrap ? inx[0] : inx[(v + 1) & 7];
    float byy = wrap ? iny[0] : iny[(v + 1) & 7];
    float cr = axx * byy - bxx * ayy;
    s += valid ? cr : 0.f;
  }
  float area = 0.5f * fabsf(s);
  return (n >= 3) ? area : 0.f;
}

// ---------------- kernel 1: decode + compacted rank-sort + AABB filter + clip ------------
// R9 structure: block (ci,s) owns mask rows i == s (mod 8). NEW: rank is
// computed only over the V valid keys (invalid keys are strictly larger than
// every valid key, so rank(valid) over valid-only == rank over all 512 —
// decision-identical). Slots >= V are never read downstream (kkey references
// only kept i < V), so only ssort needs the -inf fill there.
__global__ void __launch_bounds__(512) k_pipe(
    const float* __restrict__ logits, const float* __restrict__ regr,
    const float* __restrict__ prop,
    float* __restrict__ ssort, float* __restrict__ bsort,
    u64* __restrict__ mask) {
  int ci = blockIdx.x;
  int s = blockIdx.y;
  int b = ci / FG, c = ci - b * FG + 1;  // class 1..15
  int tid = threadIdx.x, lane = tid & 63, wv = tid >> 6;

  __shared__ __align__(16) u64 key2[NPROP + 8];     // compacted valid keys + pad
  __shared__ int rmap[NPROP];                       // orig tid -> rank
  __shared__ int cnt[8];
  __shared__ __align__(16) float crn[NPROP][8];     // 16 KB sorted corners
  __shared__ float4 aabb[NPROP];                    //  8 KB
  __shared__ float areaL[NPROP];                    //  2 KB
  __shared__ u32 stage[STAGE_CAP];                  // 16 KB
  __shared__ int lcnt;

  if (tid == 0) lcnt = 0;

  // ---- decode + softmax (bit-identical to reference path) ----
  float sc, bb[5];
  u64 k;
  {
#pragma clang fp contract(off)
    int g = b * NPROP + tid;
    const float* lg = logits + g * NCLS;
    float l[NCLS];
    float mx = -INFINITY;
#pragma unroll
    for (int q = 0; q < NCLS; ++q) { l[q] = lg[q]; mx = fmaxf(mx, l[q]); }
    float sum = 0.f, ec = 0.f;
#pragma unroll
    for (int q = 0; q < NCLS; ++q) {
      float e = expf(l[q] - mx);
      sum += e;
      if (q == c) ec = e;
    }
    sc = ec / sum;
    const float* pb = prop + g * 5;
    float xc = pb[0], yc = pb[1], w = pb[2], h = pb[3], a = pb[4];
    const float* r = regr + g * 80 + c * 5;
    float dx = r[0] / 10.0f;
    float dy = r[1] / 10.0f;
    float dw = fminf(r[2] / 5.0f, 4.135166556742356f);
    float dh = fminf(r[3] / 5.0f, 4.135166556742356f);
    float da = r[4] / 10.0f;
    bb[0] = dx * w + xc;
    bb[1] = dy * h + yc;
    bb[2] = expf(dw) * w;
    bb[3] = expf(dh) * h;
    bb[4] = da * 57.29577951308232f + a;
    float m = (sc > SCORE_T) ? sc : -INFINITY;
    k = ((u64)(~sortable_f32(m)) << 32) | (u32)tid;  // asc key = desc score, asc idx
  }
  bool val = sc > SCORE_T;
  u64 bal = __ballot(val);
  if (lane == 0) cnt[wv] = (int)__popcll(bal);
  __syncthreads();
  int base = 0, V = 0;
#pragma unroll
  for (int w = 0; w < 8; ++w) {
    int cw = cnt[w];
    base += (w < wv) ? cw : 0;
    V += cw;
  }
  if (val) key2[base + (int)__popcll(bal & ((1ull << lane) - 1ull))] = k;
  int Vpad = (V + 7) & ~7;
  if (tid < Vpad - V) key2[V + tid] = ~0ull;  // sentinel: > every real key
  __syncthreads();

  // ---- rank over valid-only keys (strictly distinct => bijective) ----
  if (tid < V) {
    u64 myk = key2[tid];
    int rank = 0;
    const ulonglong2* k2 = (const ulonglong2*)key2;
#pragma unroll 4
    for (int m = 0; m < Vpad / 2; ++m) {
      ulonglong2 kk = k2[m];  // ds_read_b128 broadcast
      rank += (kk.x < myk) ? 1 : 0;
      rank += (kk.y < myk) ? 1 : 0;
    }
    rmap[(int)(myk & 0xFFFFFFFFull)] = rank;
    if (s == 0) {  // bit-exact score recovery from the key
      u32 so = ~(u32)(myk >> 32);
      ssort[ci * NPROP + rank] = __uint_as_float(so ^ 0x80000000u);
    }
  }
  if (tid >= V && s == 0) ssort[ci * NPROP + tid] = -INFINITY;
  // zero this block's own mask rows: row = s + 8*(tid>>3), word = tid&7
  mask[((size_t)ci * NPROP + s + 8 * (tid >> 3)) * 8 + (tid & 7)] = 0ull;
  __syncthreads();

  // ---- scatter geometry by rank (exact contract-off expressions) ----
  if (val) {
    int r = rmap[tid];
    {
#pragma clang fp contract(off)
      float t = bb[4] * 0.017453292519943295f;
      float cs = cosf(t), sn = sinf(t);
      float hw = bb[2] * 0.5f, hh = bb[3] * 0.5f;
      float lx[4] = {-hw, hw, hw, -hw};
      float ly[4] = {-hh, -hh, hh, hh};
      float X[4], Y[4];
#pragma unroll
      for (int q = 0; q < 4; ++q) {
        X[q] = bb[0] + lx[q] * cs - ly[q] * sn;
        Y[q] = bb[1] + lx[q] * sn + ly[q] * cs;
      }
#pragma unroll
      for (int q = 0; q < 4; ++q) { crn[r][q] = X[q]; crn[r][4 + q] = Y[q]; }
      float xmn = fminf(fminf(X[0], X[1]), fminf(X[2], X[3]));
      float xmx = fmaxf(fmaxf(X[0], X[1]), fmaxf(X[2], X[3]));
      float ymn = fminf(fminf(Y[0], Y[1]), fminf(Y[2], Y[3]));
      float ymx = fmaxf(fmaxf(Y[0], Y[1]), fmaxf(Y[2], Y[3]));
      aabb[r] = make_float4(xmn, ymn, xmx, ymx);
      areaL[r] = bb[2] * bb[3];
      if (s == 0) {
        float* dst = bsort + ((size_t)ci * NPROP + r) * 5;
#pragma unroll
        for (int q = 0; q < 5; ++q) dst[q] = bb[q];
      }
    }
  }
  __syncthreads();

  // ---- phase 1: AABB-overlap-area filter, stage surviving pairs ----
  // IoU>0.5 needs inter > (A+B)/3 and inter <= AABB-overlap-area, so require
  // AABBinter > 0.33*(A+B) (1% slack >> fp rounding; AABB-disjoint => inter==0).
  for (int i = s; i < V; i += STRIPES) {
    float4 ai = aabb[i];
    float Ai = areaL[i];
    int j = (((i >> 6) << 6)) + tid;  // start at i's 64-chunk: fewer wasted lanes
    bool pass = false;
    if (j > i && j < V) {
      float4 aj = aabb[j];
      float ix = fminf(ai.z, aj.z) - fmaxf(ai.x, aj.x);
      float iy = fminf(ai.w, aj.w) - fmaxf(ai.y, aj.y);
      float ov = fmaxf(ix, 0.f) * fmaxf(iy, 0.f);  // >= exact quad intersection
      pass = ov > 0.33f * (Ai + areaL[j]);
    }
    u64 bal2 = __ballot(pass);
    if (bal2) {
      int base2 = 0;
      if (lane == 0) base2 = atomicAdd(&lcnt, (int)__popcll(bal2));
      base2 = __shfl(base2, 0);
      if (pass) {
        int pos = base2 + (int)__popcll(bal2 & ((1ull << lane) - 1ull));
        if (pos < STAGE_CAP) stage[pos] = ((u32)i << 9) | (u32)j;
      }
    }
  }
  __syncthreads();
  int tot = lcnt < STAGE_CAP ? lcnt : STAGE_CAP;

  // ---- phase 2: clip staged pairs, set own mask rows ----
  for (int p = tid; p < tot; p += 512) {
    u32 w = stage[p];
    int i = w >> 9, j = w & 511;
    float4 a0 = *(const float4*)&crn[i][0];
    float4 a1 = *(const float4*)&crn[i][4];
    float4 b0 = *(const float4*)&crn[j][0];
    float4 b1 = *(const float4*)&crn[j][4];
    float Ax[4] = {a0.x, a0.y, a0.z, a0.w};
    float Ay[4] = {a1.x, a1.y, a1.z, a1.w};
    float Bx[4] = {b0.x, b0.y, b0.z, b0.w};
    float By[4] = {b1.x, b1.y, b1.z, b1.w};
    float inter = inter_area_fast(Ax, Ay, Bx, By);
    float areaA = areaL[i];
    float areaB = areaL[j];
    float uni = (areaA + areaB) - inter;
    float iou = inter / fmaxf(uni, 1e-8f);
    if (iou > NMS_T)
      atomicOr(&mask[((size_t)ci * NPROP + i) * 8 + (j >> 6)], 1ull << (j & 63));
  }
}

// ---------------- kernel 2: greedy NMS scan (register-resident, prefetched) ----------------
__global__ void __launch_bounds__(256) k_nms(
    const float* __restrict__ ssort, const u64* __restrict__ mask,
    u64* __restrict__ kkey) {  // [NCI][128] sortable keys, desc, 0-filled
  int ci = blockIdx.x;
  int b = ci / FG, cfg = ci - b * FG;
  __shared__ u64 lmask[(NPROP + 4) * 8];  // 33 KB (+4 pad rows for prefetch)
  __shared__ u64 keptw[8];
  __shared__ int vcnt;
  __shared__ int wpre[8];
  int tid = threadIdx.x;
  const float* ss = ssort + ci * NPROP;
  if (tid == 0) vcnt = NPROP;
  __syncthreads();
  for (int i = tid; i < NPROP; i += 256)
    if (!(ss[i] > SCORE_T)) atomicMin(&vcnt, i);
  __syncthreads();
  int V = vcnt;
  for (int x = tid; x < V * 8; x += 256)
    lmask[x] = mask[(size_t)ci * NPROP * 8 + x];
  if (tid < 32) lmask[V * 8 + tid] = 0ull;  // pad rows V..V+3
  __syncthreads();
  if (tid == 0) {
    u64 rem[8] = {0, 0, 0, 0, 0, 0, 0, 0};
    u64 kept[8] = {0, 0, 0, 0, 0, 0, 0, 0};
    u64 buf[4][8];
#pragma unroll
    for (int d = 0; d < 4; ++d)
#pragma unroll
      for (int w = 0; w < 8; ++w) buf[d][w] = lmask[d * 8 + w];
    int kc = 0;
    bool stop = (V == 0);
#pragma unroll
    for (int w8 = 0; w8 < 8; ++w8) {
      int lim = V - (w8 << 6);
      lim = lim > 64 ? 64 : lim;
      if (!stop && lim > 0) {
        int lim4 = (lim + 3) & ~3;
        for (int bp4 = 0; bp4 < lim4 && !stop; bp4 += 4) {
#pragma unroll
          for (int d = 0; d < 4; ++d) {
            int bp = bp4 + d;
            int i = (w8 << 6) | bp;
            if (bp < lim && !stop) {
              if (!((rem[w8] >> bp) & 1ull)) {
                kept[w8] |= 1ull << bp;
#pragma unroll
                for (int w = 0; w < 8; ++w) rem[w] |= buf[d][w];
                if (++kc >= DETS) stop = true;  // first 100 kept determine output
              }
            }
#pragma unroll
            for (int w = 0; w < 8; ++w) buf[d][w] = lmask[(i + 4) * 8 + w];  // prefetch
          }
        }
      }
    }
#pragma unroll
    for (int w = 0; w < 8; ++w) keptw[w] = kept[w];
  }
  __syncthreads();
  if (tid == 0) {
    int acc = 0;
#pragma unroll
    for (int w = 0; w < 8; ++w) { wpre[w] = acc; acc += (int)__popcll(keptw[w]); }
  }
  __syncthreads();
  for (int i = tid; i < NPROP; i += 256) {
    u64 kw = keptw[i >> 6];
    if ((kw >> (i & 63)) & 1ull) {
      int rank = wpre[i >> 6] + (int)__popcll(kw & ((1ull << (i & 63)) - 1ull));
      float s = ss[i];
      u32 hi = __float_as_uint(s) ^ 0x80000000u;  // s > 0.05 > 0
      u32 flat = (u32)(cfg * NPROP + i);
      kkey[ci * 128 + rank] = ((u64)hi << 32) | (u32)(~flat);  // ties: lower flat wins max
    }
  }
  int total = wpre[7] + (int)__popcll(keptw[7]);
  for (int r = tid; r < 128; r += 256)
    if (r >= total) kkey[ci * 128 + r] = 0ull;
}

// ---------------- kernel 3: parallel rank-select top-100 ----------------
__global__ void __launch_bounds__(1024) k_topk(
    const u64* __restrict__ kkey,
    const float* __restrict__ bsort,
    float* __restrict__ out) {
  int b = blockIdx.x;  // 2 blocks, 1024 threads
  __shared__ u64 lk[FG * 128];  // 15 KiB
  __shared__ u64 res[DETS];
  for (int x = threadIdx.x; x < FG * 128; x += 1024) lk[x] = kkey[b * FG * 128 + x];
  for (int x = threadIdx.x; x < DETS; x += 1024) res[x] = 0ull;
  __syncthreads();
  for (int x = threadIdx.x; x < FG * 128; x += 1024) {
    u64 key = lk[x];
    if (key == 0ull) continue;  // real keys have hi bit set (score > 0)
    int rank = 0;
#pragma unroll
    for (int c = 0; c < FG; ++c) {
      const u64* a = &lk[c * 128];
      int pos = 0;
#pragma unroll
      for (int st = 64; st > 0; st >>= 1)
        pos += (a[pos + st - 1] > key) ? st : 0;  // pos in [0,127]
      rank += pos + ((a[pos] > key) ? 1 : 0);
    }
    if (rank < DETS) res[rank] = key;
  }
  __syncthreads();
  if (threadIdx.x < DETS) {
    u64 key = res[threadIdx.x];
    float* o = out + ((size_t)b * DETS + threadIdx.x) * 6;
    if (key == 0ull) {
#pragma unroll
      for (int q = 0; q < 6; ++q) o[q] = 0.f;
    } else {
      u32 flat = ~(u32)(key & 0xFFFFFFFFull);
      int cfg = flat >> 9, pos = flat & 511;
      const float* bx = bsort + (((size_t)b * FG + cfg) * NPROP + pos) * 5;
#pragma unroll
      for (int q = 0; q < 5; ++q) o[q] = bx[q];
      o[5] = __uint_as_float((u32)(key >> 32) ^ 0x80000000u);
    }
  }
}

extern "C" void kernel_launch(void* const* d_in, const int* in_sizes, int n_in,
                              void* d_out, int out_size, void* d_ws, size_t ws_size,
                              hipStream_t stream) {
  const float* logits = (const float*)d_in[0];
  const float* regr   = (const float*)d_in[1];
  const float* prop   = (const float*)d_in[2];
  float* out = (float*)d_out;

  float* ssort = (float*)d_ws;                     // 15360 f
  float* bsort = ssort + NCI * NPROP;              // 76800 f
  u64* kkey    = (u64*)(bsort + NCI * NPROP * 5);  // 3840 u64 (368640 B offset, 8B-aligned)
  u64* mask    = kkey + NCI * 128;                 // 122880 u64 (~1.4 MB total)

  hipLaunchKernelGGL(k_pipe, dim3(NCI, STRIPES), dim3(512), 0, stream,
                     logits, regr, prop, ssort, bsort, mask);
  hipLaunchKernelGGL(k_nms, dim3(NCI), dim3(256), 0, stream, ssort, mask, kkey);
  hipLaunchKernelGGL(k_topk, dim3(2), dim3(1024), 0, stream, kkey, bsort, out);
}